// Round 1
// baseline (1855.959 us; speedup 1.0000x reference)
//
#include <hip/hip_runtime.h>

// trajectory2seq: 2-layer GRU encoder (S=128) + attention decoder (6 steps)
// Round 1: correctness-first fp32 implementation.
//   enc_kernel: 128 blocks x 512 thr; lane=batch element, 8 waves split gate rows,
//               weights via wave-uniform scalar loads, h-state in padded LDS.
//   dec_kernel: 128 blocks x 256 thr; same layout; attention reads enc[t][k][b]
//               (lane-contiguous); softmax + first-index argmax matching numpy.
// ws layout: enc [128][20][8192] fp32 (83.9MB) + hfin0/hfin1 [8192][20] (1.3MB).

#define HN 20
#define DIN 64
#define NVOCAB 128
#define NB 8192
#define NS 128
#define NDEC 6

#define HID_OFF (NB * NDEC * NVOCAB)      // 6291456
#define ATTN_OFF (HID_OFF + 2 * NB * HN)  // 6619136

__device__ __forceinline__ float sigf(float x) {
    return 1.0f / (1.0f + __expf(-x));
}

__global__ __launch_bounds__(512)
void enc_kernel(const float* __restrict__ x,
                const float* __restrict__ Wih0, const float* __restrict__ Whh0,
                const float* __restrict__ bih0, const float* __restrict__ bhh0,
                const float* __restrict__ Wih1, const float* __restrict__ Whh1,
                const float* __restrict__ bih1, const float* __restrict__ bhh1,
                float* __restrict__ enc, float* __restrict__ hf0,
                float* __restrict__ hf1)
{
    __shared__ float xs[64][68];    // x tile, b128-aligned rows
    __shared__ float h0s[64][21];   // pad 21: conflict-free per-lane rows
    __shared__ float h1s[64][21];
    __shared__ float gs[64][81];    // gate pre-activations (ir+hr,iz+hz | inn | hn)

    const int tid = threadIdx.x;
    const int l   = tid & 63;
    const int w   = __builtin_amdgcn_readfirstlane(tid >> 6);  // wave id 0..7
    const int b0  = blockIdx.x * 64;

    for (int i = tid; i < 64 * 21; i += 512) {
        (&h0s[0][0])[i] = 0.0f;
        (&h1s[0][0])[i] = 0.0f;
    }
    __syncthreads();

    for (int t = 0; t < NS; ++t) {
        // ---- stage x[b0..b0+63][t][0..63] into LDS (coalesced float4) ----
        {
            const float4* xv = (const float4*)x;
            #pragma unroll
            for (int it = 0; it < 2; ++it) {
                int c = it * 512 + tid;
                int r = c >> 4, q = c & 15;
                float4 v = xv[((b0 + r) * NS + t) * 16 + q];
                *(float4*)(&xs[r][q * 4]) = v;
            }
        }
        __syncthreads();

        // ---- layer 0: gates j = w + 8*jj (wave-uniform j -> scalar W loads) ----
        {
            float xr[DIN];
            #pragma unroll
            for (int q = 0; q < 16; ++q) {
                float4 v = *(const float4*)(&xs[l][q * 4]);
                xr[4*q] = v.x; xr[4*q+1] = v.y; xr[4*q+2] = v.z; xr[4*q+3] = v.w;
            }
            float hr[HN];
            #pragma unroll
            for (int i = 0; i < HN; ++i) hr[i] = h0s[l][i];

            for (int j = w; j < 60; j += 8) {
                float ax = bih0[j];
                float ah = bhh0[j];
                #pragma unroll
                for (int i = 0; i < DIN; ++i) ax += Wih0[j * DIN + i] * xr[i];
                #pragma unroll
                for (int i = 0; i < HN; ++i) ah += Whh0[j * HN + i] * hr[i];
                if (j < 40) gs[l][j] = ax + ah;
                else { gs[l][j] = ax; gs[l][j + 20] = ah; }  // keep inn, hn split
            }
        }
        __syncthreads();

        for (int k = w; k < HN; k += 8) {
            float r = sigf(gs[l][k]);
            float z = sigf(gs[l][20 + k]);
            float n = tanhf(gs[l][40 + k] + r * gs[l][60 + k]);
            float hnew = (1.0f - z) * n + z * h0s[l][k];
            h0s[l][k] = hnew;
            if (t == NS - 1) hf0[(b0 + l) * HN + k] = hnew;
        }
        __syncthreads();

        // ---- layer 1 ----
        {
            float er[HN], hr[HN];
            #pragma unroll
            for (int i = 0; i < HN; ++i) { er[i] = h0s[l][i]; hr[i] = h1s[l][i]; }

            for (int j = w; j < 60; j += 8) {
                float ax = bih1[j];
                float ah = bhh1[j];
                #pragma unroll
                for (int i = 0; i < HN; ++i) ax += Wih1[j * HN + i] * er[i];
                #pragma unroll
                for (int i = 0; i < HN; ++i) ah += Whh1[j * HN + i] * hr[i];
                if (j < 40) gs[l][j] = ax + ah;
                else { gs[l][j] = ax; gs[l][j + 20] = ah; }
            }
        }
        __syncthreads();

        for (int k = w; k < HN; k += 8) {
            float r = sigf(gs[l][k]);
            float z = sigf(gs[l][20 + k]);
            float n = tanhf(gs[l][40 + k] + r * gs[l][60 + k]);
            float hnew = (1.0f - z) * n + z * h1s[l][k];
            h1s[l][k] = hnew;
            enc[(t * HN + k) * NB + b0 + l] = hnew;   // [t][k][b]: lane-coalesced
            if (t == NS - 1) hf1[(b0 + l) * HN + k] = hnew;
        }
        __syncthreads();
    }
}

__global__ __launch_bounds__(256)
void dec_kernel(const float* __restrict__ dWih0, const float* __restrict__ dWhh0,
                const float* __restrict__ dbih0, const float* __restrict__ dbhh0,
                const float* __restrict__ dWih1, const float* __restrict__ dWhh1,
                const float* __restrict__ dbih1, const float* __restrict__ dbhh1,
                const float* __restrict__ emb,  const float* __restrict__ qW,
                const float* __restrict__ qb,   const float* __restrict__ combW,
                const float* __restrict__ combb, const float* __restrict__ outW,
                const float* __restrict__ outb,
                const float* __restrict__ enc, const float* __restrict__ hf0,
                const float* __restrict__ hf1, float* __restrict__ out)
{
    __shared__ float hd0[64][21], hd1[64][21];
    __shared__ float bufA[64][129];  // gs (GRU) -> softmax weights -> logits
    __shared__ float bufB[64][43];   // emb/query/context [0..20], comb [21..41]
    __shared__ float red[64][8];     // softmax max [0..3] / sum [4..7]
    __shared__ float lmax[64][4];
    __shared__ int   lidx[64][4];
    __shared__ int   toks[64];

    const int tid = threadIdx.x;
    const int l   = tid & 63;
    const int w   = __builtin_amdgcn_readfirstlane(tid >> 6);  // wave id 0..3
    const int b0  = blockIdx.x * 64;

    for (int idx = tid; idx < 64 * HN; idx += 256) {
        int e = idx / HN, k = idx % HN;
        hd0[e][k] = hf0[b0 * HN + idx];
        hd1[e][k] = hf1[b0 * HN + idx];
    }
    if (tid < 64) toks[tid] = 0;
    __syncthreads();

    for (int s = 0; s < NDEC; ++s) {
        // ---- embedding ----
        for (int k = w; k < HN; k += 4) bufB[l][k] = emb[toks[l] * HN + k];
        __syncthreads();

        // ---- GRU layer 0 (input = embedding) ----
        {
            float er[HN], hr[HN];
            #pragma unroll
            for (int i = 0; i < HN; ++i) { er[i] = bufB[l][i]; hr[i] = hd0[l][i]; }
            for (int j = w; j < 60; j += 4) {
                float ax = dbih0[j], ah = dbhh0[j];
                #pragma unroll
                for (int i = 0; i < HN; ++i) ax += dWih0[j * HN + i] * er[i];
                #pragma unroll
                for (int i = 0; i < HN; ++i) ah += dWhh0[j * HN + i] * hr[i];
                if (j < 40) bufA[l][j] = ax + ah;
                else { bufA[l][j] = ax; bufA[l][j + 20] = ah; }
            }
        }
        __syncthreads();
        for (int k = w; k < HN; k += 4) {
            float r = sigf(bufA[l][k]);
            float z = sigf(bufA[l][20 + k]);
            float n = tanhf(bufA[l][40 + k] + r * bufA[l][60 + k]);
            hd0[l][k] = (1.0f - z) * n + z * hd0[l][k];
        }
        __syncthreads();

        // ---- GRU layer 1 (input = hd0 new) ----
        {
            float er[HN], hr[HN];
            #pragma unroll
            for (int i = 0; i < HN; ++i) { er[i] = hd0[l][i]; hr[i] = hd1[l][i]; }
            for (int j = w; j < 60; j += 4) {
                float ax = dbih1[j], ah = dbhh1[j];
                #pragma unroll
                for (int i = 0; i < HN; ++i) ax += dWih1[j * HN + i] * er[i];
                #pragma unroll
                for (int i = 0; i < HN; ++i) ah += dWhh1[j * HN + i] * hr[i];
                if (j < 40) bufA[l][j] = ax + ah;
                else { bufA[l][j] = ax; bufA[l][j + 20] = ah; }
            }
        }
        __syncthreads();
        for (int k = w; k < HN; k += 4) {
            float r = sigf(bufA[l][k]);
            float z = sigf(bufA[l][20 + k]);
            float n = tanhf(bufA[l][40 + k] + r * bufA[l][60 + k]);
            hd1[l][k] = (1.0f - z) * n + z * hd1[l][k];
        }
        __syncthreads();

        // cache buf = hd1 (stable for the rest of this step)
        float h1r[HN];
        #pragma unroll
        for (int i = 0; i < HN; ++i) h1r[i] = hd1[l][i];

        // ---- query ----
        for (int k = w; k < HN; k += 4) {
            float a = qb[k];
            #pragma unroll
            for (int i = 0; i < HN; ++i) a += qW[k * HN + i] * h1r[i];
            bufB[l][k] = a;
        }
        __syncthreads();

        // ---- scores + softmax (t split: wave w owns t in [32w, 32w+32)) ----
        float sreg[32];
        {
            float qr[HN];
            #pragma unroll
            for (int i = 0; i < HN; ++i) qr[i] = bufB[l][i];
            float mx = -1e30f;
            const int t0 = w * 32;
            for (int u = 0; u < 32; ++u) {
                int t = t0 + u;
                float a = 0.0f;
                #pragma unroll
                for (int k = 0; k < HN; ++k)
                    a += qr[k] * enc[(t * HN + k) * NB + b0 + l];
                sreg[u] = a;
                mx = fmaxf(mx, a);
            }
            red[l][w] = mx;
            __syncthreads();
            float M = fmaxf(fmaxf(red[l][0], red[l][1]), fmaxf(red[l][2], red[l][3]));
            float ssum = 0.0f;
            for (int u = 0; u < 32; ++u) {
                float e = __expf(sreg[u] - M);
                sreg[u] = e;
                ssum += e;
            }
            red[l][4 + w] = ssum;
            __syncthreads();
            float S = red[l][4] + red[l][5] + red[l][6] + red[l][7];
            float inv = 1.0f / S;
            for (int u = 0; u < 32; ++u) bufA[l][t0 + u] = sreg[u] * inv;
        }
        __syncthreads();

        // ---- write attention weights (coalesced: lane-contiguous t) ----
        for (int it = 0; it < 32; ++it) {
            int idx = it * 256 + tid;
            int e = idx >> 7, tt = idx & 127;
            out[ATTN_OFF + s * (NB * NS) + (b0 + e) * NS + tt] = bufA[e][tt];
        }

        // ---- context (k split: wave w owns k = w + 4c) ----
        {
            float acc[5];
            #pragma unroll
            for (int c = 0; c < 5; ++c) acc[c] = 0.0f;
            for (int t = 0; t < NS; ++t) {
                float wt = bufA[l][t];
                #pragma unroll
                for (int c = 0; c < 5; ++c) {
                    int k = w + 4 * c;
                    acc[c] += wt * enc[(t * HN + k) * NB + b0 + l];
                }
            }
            #pragma unroll
            for (int c = 0; c < 5; ++c) bufB[l][w + 4 * c] = acc[c];
        }
        __syncthreads();

        // ---- comb = [buf, ctx] @ comb_W.T + comb_b ----
        {
            float asr[HN];
            #pragma unroll
            for (int i = 0; i < HN; ++i) asr[i] = bufB[l][i];
            for (int k = w; k < HN; k += 4) {
                float a = combb[k];
                #pragma unroll
                for (int i = 0; i < HN; ++i) a += combW[k * 2 * HN + i] * h1r[i];
                #pragma unroll
                for (int i = 0; i < HN; ++i) a += combW[k * 2 * HN + HN + i] * asr[i];
                bufB[l][21 + k] = a;
            }
        }
        __syncthreads();

        // ---- logits + per-wave argmax (v split: wave w owns [32w,32w+32)) ----
        {
            float cr[HN];
            #pragma unroll
            for (int i = 0; i < HN; ++i) cr[i] = bufB[l][21 + i];
            float best = -1e30f; int bi = 0;
            for (int u = 0; u < 32; ++u) {
                int v = w * 32 + u;
                float a = outb[v];
                #pragma unroll
                for (int k = 0; k < HN; ++k) a += outW[v * HN + k] * cr[k];
                bufA[l][v] = a;
                if (a > best) { best = a; bi = v; }   // strict >: first index wins
            }
            lmax[l][w] = best;
            lidx[l][w] = bi;
        }
        __syncthreads();

        // ---- write logits (coalesced) + combine argmax ----
        for (int it = 0; it < 32; ++it) {
            int idx = it * 256 + tid;
            int e = idx >> 7, v = idx & 127;
            out[(b0 + e) * (NDEC * NVOCAB) + s * NVOCAB + v] = bufA[e][v];
        }
        if (tid < 64) {
            float bb = lmax[tid][0]; int ii = lidx[tid][0];
            #pragma unroll
            for (int ww = 1; ww < 4; ++ww) {
                if (lmax[tid][ww] > bb) { bb = lmax[tid][ww]; ii = lidx[tid][ww]; }
            }
            toks[tid] = ii;
        }
        __syncthreads();
    }

    // ---- final hidden state [2][B][H] ----
    for (int idx = tid; idx < 64 * HN; idx += 256) {
        int e = idx / HN, k = idx % HN;
        out[HID_OFF + b0 * HN + idx] = hd0[e][k];
        out[HID_OFF + NB * HN + b0 * HN + idx] = hd1[e][k];
    }
}

extern "C" void kernel_launch(void* const* d_in, const int* in_sizes, int n_in,
                              void* d_out, int out_size, void* d_ws, size_t ws_size,
                              hipStream_t stream)
{
    const float* x        = (const float*)d_in[0];
    const float* eWih0    = (const float*)d_in[1];
    const float* eWhh0    = (const float*)d_in[2];
    const float* ebih0    = (const float*)d_in[3];
    const float* ebhh0    = (const float*)d_in[4];
    const float* eWih1    = (const float*)d_in[5];
    const float* eWhh1    = (const float*)d_in[6];
    const float* ebih1    = (const float*)d_in[7];
    const float* ebhh1    = (const float*)d_in[8];
    const float* dWih0    = (const float*)d_in[9];
    const float* dWhh0    = (const float*)d_in[10];
    const float* dbih0    = (const float*)d_in[11];
    const float* dbhh0    = (const float*)d_in[12];
    const float* dWih1    = (const float*)d_in[13];
    const float* dWhh1    = (const float*)d_in[14];
    const float* dbih1    = (const float*)d_in[15];
    const float* dbhh1    = (const float*)d_in[16];
    const float* emb      = (const float*)d_in[17];
    const float* qW       = (const float*)d_in[18];
    const float* qb       = (const float*)d_in[19];
    const float* combW    = (const float*)d_in[20];
    const float* combb    = (const float*)d_in[21];
    const float* outW     = (const float*)d_in[22];
    const float* outb     = (const float*)d_in[23];

    // workspace: enc [NS][HN][NB] + hfin0 [NB][HN] + hfin1 [NB][HN]
    const size_t need = ((size_t)NS * HN * NB + 2 * (size_t)NB * HN) * sizeof(float);
    if (ws_size < need) return;  // cannot run without scratch; fail visibly

    float* ws  = (float*)d_ws;
    float* enc = ws;
    float* hf0 = ws + (size_t)NS * HN * NB;
    float* hf1 = hf0 + (size_t)NB * HN;

    enc_kernel<<<128, 512, 0, stream>>>(x, eWih0, eWhh0, ebih0, ebhh0,
                                        eWih1, eWhh1, ebih1, ebhh1,
                                        enc, hf0, hf1);
    dec_kernel<<<128, 256, 0, stream>>>(dWih0, dWhh0, dbih0, dbhh0,
                                        dWih1, dWhh1, dbih1, dbhh1,
                                        emb, qW, qb, combW, combb, outW, outb,
                                        enc, hf0, hf1, (float*)d_out);
}